// Round 5
// baseline (482.604 us; speedup 1.0000x reference)
//
#include <hip/hip_runtime.h>

#define SDIM 2048
#define DDIM 512
#define NB 8

typedef __bf16 bf16x8 __attribute__((ext_vector_type(8)));
typedef float f32x4 __attribute__((ext_vector_type(4)));
#define AS1 __attribute__((address_space(1)))
#define AS3 __attribute__((address_space(3)))

__device__ __forceinline__ ushort f2bf(float f) {
  unsigned u = __float_as_uint(f);
  u = (u + 0x7FFFu + ((u >> 16) & 1u)) >> 16;  // RNE
  return (ushort)u;
}

// ---- fused prepass: blocks [0,2048) transpose V -> bf16 V^T; [2048,3072) K -> bf16
__global__ void prep(const float* __restrict__ K, const float* __restrict__ V,
                     ushort* __restrict__ Kb, ushort* __restrict__ Vt) {
  int bid = blockIdx.x;
  int tid = threadIdx.x;
  if (bid < 2048) {
    __shared__ float T[64][65];
    int b  = bid >> 8;
    int st = (bid >> 3) & 31;
    int dt = bid & 7;
    int r  = tid >> 4, c4 = (tid & 15) << 2;
    const float* src = V + ((size_t)b * SDIM + st * 64) * DDIM + dt * 64;
    #pragma unroll
    for (int i = 0; i < 4; ++i) {
      float4 v = *(const float4*)(src + (size_t)(r + i * 16) * DDIM + c4);
      T[r + i * 16][c4 + 0] = v.x; T[r + i * 16][c4 + 1] = v.y;
      T[r + i * 16][c4 + 2] = v.z; T[r + i * 16][c4 + 3] = v.w;
    }
    __syncthreads();
    ushort* dst = Vt + ((size_t)b * DDIM + dt * 64) * SDIM + st * 64;
    #pragma unroll
    for (int i = 0; i < 4; ++i) {
      int dr = r + i * 16;
      ushort4 o;
      o.x = f2bf(T[c4 + 0][dr]); o.y = f2bf(T[c4 + 1][dr]);
      o.z = f2bf(T[c4 + 2][dr]); o.w = f2bf(T[c4 + 3][dr]);
      *(ushort4*)(dst + (size_t)dr * SDIM + c4) = o;
    }
  } else {
    const long N4 = (long)NB * SDIM * DDIM / 4;
    const long stride = 1024L * 256;
    for (long i = (long)(bid - 2048) * 256 + tid; i < N4; i += stride) {
      float4 k = ((const float4*)K)[i];
      ushort4 o;
      o.x = f2bf(k.x); o.y = f2bf(k.y); o.z = f2bf(k.z); o.w = f2bf(k.w);
      ((ushort4*)Kb)[i] = o;
    }
  }
}

// ---- flash attention: 4-wave blocks, QBLK=32, KBLK=64, 512 blocks (2/CU).
// No K-split, no merge. K single-buffered in 64KB swizzled LDS (global_load_lds,
// restaged at [B], waited at [A]); V direct-from-L2 full-line frags; l via
// ones-column MFMA; defer-max THR=8. Two co-resident blocks/CU with
// independent barriers provide the latency overlap the lockstep design lacked.
__global__ __launch_bounds__(256, 2) void attn(
    const float* __restrict__ Qf, const ushort* __restrict__ Kb,
    const ushort* __restrict__ Vt, float* __restrict__ out) {
  __shared__ __align__(16) char Ksh[64 * 1024];
  __shared__ __align__(16) ushort Psh[32 * 72];     // row stride 144B (pad 8)
  __shared__ float mrow[2][32], pmx[2][32];

  const int bid = blockIdx.x;
  const int b   = bid & 7;                  // batch -> XCD affinity
  const int p   = bid >> 3;                 // 0..63
  const int t   = (p < 32) ? p : (95 - p);  // CU-pair (p, p+32) sums to 63
  const int q0  = t << 5;
  const int tid = threadIdx.x;
  const int w   = tid >> 6;
  const int lane = tid & 63;
  const int g    = (lane >> 4) & 3;
  const int m16  = lane & 15;
  const int qs   = w >> 1;                  // QK^T q-subtile
  const int ks   = w & 1;                   // QK^T k-half (32 of 64)
  const int dw0  = w << 7;                  // PV d-slice base

  const ushort* kbb = Kb + (size_t)b * SDIM * DDIM;
  const ushort* vtb = Vt + (size_t)b * DDIM * SDIM;

  // Q fragments: fp32 -> bf16 in-reg, scaled by 1/sqrt(S)
  const float qscale = 0.022097086912079608f;
  bf16x8 qf[16];
  {
    const float* qrow = Qf + ((size_t)b * SDIM + q0 + qs * 16 + m16) * DDIM + g * 8;
    #pragma unroll
    for (int ds = 0; ds < 16; ++ds) {
      float4 u = *(const float4*)(qrow + ds * 32);
      float4 x = *(const float4*)(qrow + ds * 32 + 4);
      union { ushort us[8]; bf16x8 v; } pk;
      pk.us[0] = f2bf(u.x * qscale); pk.us[1] = f2bf(u.y * qscale);
      pk.us[2] = f2bf(u.z * qscale); pk.us[3] = f2bf(u.w * qscale);
      pk.us[4] = f2bf(x.x * qscale); pk.us[5] = f2bf(x.y * qscale);
      pk.us[6] = f2bf(x.z * qscale); pk.us[7] = f2bf(x.w * qscale);
      qf[ds] = pk.v;
    }
  }

  if (tid < 32) mrow[0][tid] = -1e30f;

  union { ushort us[8]; bf16x8 v; } onesu;
  #pragma unroll
  for (int i = 0; i < 8; ++i) onesu.us[i] = 0x3F80;
  const bf16x8 ones = onesu.v;
  const f32x4 zero = {0.f, 0.f, 0.f, 0.f};
  f32x4 acc[2][8];
  f32x4 acc1[2];
  #pragma unroll
  for (int qt = 0; qt < 2; ++qt) {
    acc1[qt] = zero;
    #pragma unroll
    for (int nt = 0; nt < 8; ++nt) acc[qt][nt] = zero;
  }

  // prologue: stage K tile 0 (64 rows; swizzle byte=(d*2)^((j&7)<<4))
  #pragma unroll
  for (int ji = 0; ji < 16; ++ji) {
    int j = w * 16 + ji;
    const ushort* src = kbb + (size_t)j * DDIM + ((lane ^ (ji & 7)) << 3);
    __builtin_amdgcn_global_load_lds((const AS1 void*)src,
        (AS3 void*)(Ksh + j * 1024), 16, 0, 0);
  }
  asm volatile("s_waitcnt vmcnt(0) lgkmcnt(0)" ::: "memory");
  __builtin_amdgcn_s_barrier();

  const int i_row = q0 + qs * 16 + g * 4;
  const int T = (t + 2) >> 1;               // number of 64-wide k-tiles

  for (int i = 0; i < T; ++i) {
    const int k0 = i << 6;
    const int pp = i & 1;

    // V fragments (both 32-k halves of the same 128B lines), full-iter slack
    bf16x8 vb[2][8];
    #pragma unroll
    for (int ksl = 0; ksl < 2; ++ksl)
      #pragma unroll
      for (int nt = 0; nt < 8; ++nt)
        vb[ksl][nt] = *(const bf16x8*)(vtb + (size_t)(dw0 + nt * 16 + m16) * SDIM
                                       + k0 + ksl * 32 + g * 8);

    // ---- QK^T: 32 rows x 64 k; wave = (qs rows) x (ks 32-k half) ----
    f32x4 sA0 = zero, sA1 = zero, sB0 = zero, sB1 = zero;
    const char* kpA = Ksh + (ks * 32 + m16) * 1024;
    const char* kpB = Ksh + (ks * 32 + 16 + m16) * 1024;
    const unsigned ksw = (unsigned)((m16 & 7) << 4);
    __builtin_amdgcn_s_setprio(1);
    #pragma unroll
    for (int ds = 0; ds < 16; ds += 2) {
      const unsigned o0 = ((unsigned)(ds * 64 + g * 16)) ^ ksw;
      const unsigned o1 = ((unsigned)((ds + 1) * 64 + g * 16)) ^ ksw;
      sA0 = __builtin_amdgcn_mfma_f32_16x16x32_bf16(qf[ds], *(const bf16x8*)(kpA + o0), sA0, 0, 0, 0);
      sB0 = __builtin_amdgcn_mfma_f32_16x16x32_bf16(qf[ds], *(const bf16x8*)(kpB + o0), sB0, 0, 0, 0);
      sA1 = __builtin_amdgcn_mfma_f32_16x16x32_bf16(qf[ds + 1], *(const bf16x8*)(kpA + o1), sA1, 0, 0, 0);
      sB1 = __builtin_amdgcn_mfma_f32_16x16x32_bf16(qf[ds + 1], *(const bf16x8*)(kpB + o1), sB1, 0, 0, 0);
    }
    __builtin_amdgcn_s_setprio(0);

    const bool dia = (i == T - 1);
    float sc[2][4];
    #pragma unroll
    for (int cset = 0; cset < 2; ++cset) {
      const int j_col = k0 + ks * 32 + cset * 16 + m16;
      #pragma unroll
      for (int jj = 0; jj < 4; ++jj) {
        float d = (float)(i_row + jj - j_col);
        float bias = __builtin_amdgcn_rcpf(fmaf(0.2f * d, d, 1.0f));
        float s = (cset ? (sB0[jj] + sB1[jj]) : (sA0[jj] + sA1[jj])) + bias;
        if (dia && (j_col > i_row + jj)) s = -1e30f;
        sc[cset][jj] = s;
      }
    }

    // row max over this wave's 64 k-cols -> pmx[ks]
    #pragma unroll
    for (int jj = 0; jj < 4; ++jj) {
      float v = fmaxf(sc[0][jj], sc[1][jj]);
      v = fmaxf(v, __shfl_xor(v, 1));
      v = fmaxf(v, __shfl_xor(v, 2));
      v = fmaxf(v, __shfl_xor(v, 4));
      v = fmaxf(v, __shfl_xor(v, 8));
      if (m16 == 0) pmx[ks][qs * 16 + g * 4 + jj] = v;
    }
    asm volatile("s_waitcnt lgkmcnt(0)" ::: "memory");
    __builtin_amdgcn_s_barrier();                    // [B] pmax visible; Ksh reads done

    // restage K(i+1): slack = softmax + PV, waited at [A]
    if (i + 1 < T) {
      #pragma unroll
      for (int ji = 0; ji < 16; ++ji) {
        int j = w * 16 + ji;
        const ushort* src = kbb + (size_t)(k0 + 64 + j) * DDIM + ((lane ^ (ji & 7)) << 3);
        __builtin_amdgcn_global_load_lds((const AS1 void*)src,
            (AS3 void*)(Ksh + j * 1024), 16, 0, 0);
      }
    }

    // ---- online softmax (row = lane&31) ----
    const int row = lane & 31;
    float mo = mrow[pp][row];
    float tm = fmaxf(pmx[0][row], pmx[1][row]);
    bool upd = tm > mo + 8.0f;                       // defer-max THR=8
    float mn = upd ? tm : mo;
    float rr = upd ? __expf(mo - tm) : 1.0f;
    if (w == 0 && lane < 32) mrow[pp ^ 1][row] = mn;

    #pragma unroll
    for (int cset = 0; cset < 2; ++cset)
      #pragma unroll
      for (int jj = 0; jj < 4; ++jj) {
        float mq = __shfl(mn, qs * 16 + g * 4 + jj);
        float pv = __expf(sc[cset][jj] - mq);
        Psh[(qs * 16 + g * 4 + jj) * 72 + ks * 32 + cset * 16 + m16] = f2bf(pv);
      }

    if (!__all(rr == 1.0f)) {
      #pragma unroll
      for (int qt = 0; qt < 2; ++qt)
        #pragma unroll
        for (int jj = 0; jj < 4; ++jj) {
          float r2 = __shfl(rr, qt * 16 + g * 4 + jj);
          #pragma unroll
          for (int nt = 0; nt < 8; ++nt) acc[qt][nt][jj] *= r2;
          acc1[qt][jj] *= r2;
        }
    }
    asm volatile("s_waitcnt lgkmcnt(0)" ::: "memory");
    __builtin_amdgcn_s_barrier();                    // [C] Psh visible

    // ---- PV: O[32 q][128 d] += P[32x64] * V[64x128]; ones column for l ----
    bf16x8 pa[2][2];
    #pragma unroll
    for (int qt = 0; qt < 2; ++qt)
      #pragma unroll
      for (int ksl = 0; ksl < 2; ++ksl)
        pa[qt][ksl] = *(const bf16x8*)((const char*)Psh + (qt * 16 + m16) * 144
                                        + ksl * 64 + g * 16);
    __builtin_amdgcn_s_setprio(1);
    #pragma unroll
    for (int nt = 0; nt < 8; ++nt) {
      acc[0][nt] = __builtin_amdgcn_mfma_f32_16x16x32_bf16(pa[0][0], vb[0][nt], acc[0][nt], 0, 0, 0);
      acc[1][nt] = __builtin_amdgcn_mfma_f32_16x16x32_bf16(pa[1][0], vb[0][nt], acc[1][nt], 0, 0, 0);
      acc[0][nt] = __builtin_amdgcn_mfma_f32_16x16x32_bf16(pa[0][1], vb[1][nt], acc[0][nt], 0, 0, 0);
      acc[1][nt] = __builtin_amdgcn_mfma_f32_16x16x32_bf16(pa[1][1], vb[1][nt], acc[1][nt], 0, 0, 0);
    }
    acc1[0] = __builtin_amdgcn_mfma_f32_16x16x32_bf16(pa[0][0], ones, acc1[0], 0, 0, 0);
    acc1[1] = __builtin_amdgcn_mfma_f32_16x16x32_bf16(pa[1][0], ones, acc1[1], 0, 0, 0);
    acc1[0] = __builtin_amdgcn_mfma_f32_16x16x32_bf16(pa[0][1], ones, acc1[0], 0, 0, 0);
    acc1[1] = __builtin_amdgcn_mfma_f32_16x16x32_bf16(pa[1][1], ones, acc1[1], 0, 0, 0);
    __builtin_amdgcn_s_setprio(0);

    // [A] K(i+1) landed; Psh consumed by all waves
    asm volatile("s_waitcnt vmcnt(0) lgkmcnt(0)" ::: "memory");
    __builtin_amdgcn_s_barrier();
  }

  // epilogue: fully register-resident (l = ones-column accumulator)
  #pragma unroll
  for (int qt = 0; qt < 2; ++qt) {
    #pragma unroll
    for (int jj = 0; jj < 4; ++jj) {
      float inv = 1.0f / acc1[qt][jj];
      float* orow = out + ((size_t)b * SDIM + q0 + qt * 16 + g * 4 + jj) * DDIM + dw0 + m16;
      #pragma unroll
      for (int nt = 0; nt < 8; ++nt)
        orow[nt * 16] = acc[qt][nt][jj] * inv;
    }
  }
}

extern "C" void kernel_launch(void* const* d_in, const int* in_sizes, int n_in,
                              void* d_out, int out_size, void* d_ws, size_t ws_size,
                              hipStream_t stream) {
  const float* Q = (const float*)d_in[0];
  const float* K = (const float*)d_in[1];
  const float* V = (const float*)d_in[2];
  float* out = (float*)d_out;
  ushort* Kb = (ushort*)d_ws;                                  // 16.78 MB
  ushort* Vt = Kb + (size_t)NB * SDIM * DDIM;                  // 16.78 MB
  prep<<<3072, 256, 0, stream>>>(K, V, Kb, Vt);
  attn<<<512, 256, 0, stream>>>(Q, Kb, Vt, out);
}

// Round 7
// 445.868 us; speedup vs baseline: 1.0824x; 1.0824x over previous
//
#include <hip/hip_runtime.h>

#define SDIM 2048
#define DDIM 512
#define NB 8

typedef __bf16 bf16x8 __attribute__((ext_vector_type(8)));
typedef float f32x4 __attribute__((ext_vector_type(4)));
#define AS1 __attribute__((address_space(1)))
#define AS3 __attribute__((address_space(3)))

__device__ __forceinline__ ushort f2bf(float f) {
  unsigned u = __float_as_uint(f);
  u = (u + 0x7FFFu + ((u >> 16) & 1u)) >> 16;  // RNE
  return (ushort)u;
}

// ---- fused prepass: blocks [0,2048) transpose V -> bf16 V^T; [2048,3072) K -> bf16
__global__ void prep(const float* __restrict__ K, const float* __restrict__ V,
                     ushort* __restrict__ Kb, ushort* __restrict__ Vt) {
  int bid = blockIdx.x;
  int tid = threadIdx.x;
  if (bid < 2048) {
    __shared__ float T[64][65];
    int b  = bid >> 8;
    int st = (bid >> 3) & 31;
    int dt = bid & 7;
    int r  = tid >> 4, c4 = (tid & 15) << 2;
    const float* src = V + ((size_t)b * SDIM + st * 64) * DDIM + dt * 64;
    #pragma unroll
    for (int i = 0; i < 4; ++i) {
      float4 v = *(const float4*)(src + (size_t)(r + i * 16) * DDIM + c4);
      T[r + i * 16][c4 + 0] = v.x; T[r + i * 16][c4 + 1] = v.y;
      T[r + i * 16][c4 + 2] = v.z; T[r + i * 16][c4 + 3] = v.w;
    }
    __syncthreads();
    ushort* dst = Vt + ((size_t)b * DDIM + dt * 64) * SDIM + st * 64;
    #pragma unroll
    for (int i = 0; i < 4; ++i) {
      int dr = r + i * 16;
      ushort4 o;
      o.x = f2bf(T[c4 + 0][dr]); o.y = f2bf(T[c4 + 1][dr]);
      o.z = f2bf(T[c4 + 2][dr]); o.w = f2bf(T[c4 + 3][dr]);
      *(ushort4*)(dst + (size_t)dr * SDIM + c4) = o;
    }
  } else {
    const long N4 = (long)NB * SDIM * DDIM / 4;
    const long stride = 1024L * 256;
    for (long i = (long)(bid - 2048) * 256 + tid; i < N4; i += stride) {
      float4 k = ((const float4*)K)[i];
      ushort4 o;
      o.x = f2bf(k.x); o.y = f2bf(k.y); o.z = f2bf(k.z); o.w = f2bf(k.w);
      ((ushort4*)Kb)[i] = o;
    }
  }
}

// ---- flash attention: 4-wave blocks, QBLK=32, KBLK=64, 512 blocks (2/CU).
// Spill-free liveness plan: V loaded JIT in two 32-k halves (vb0 at iter top,
// vb1 issued after [B] BEFORE the K-restage so its wait is vmcnt(16) and the
// K prefetch stays in flight); P-fragments loaded per half. K single-buffered
// in 64KB swizzled LDS; l via ones-column MFMA; defer-max THR=8.
__global__ __launch_bounds__(256, 2) void attn(
    const float* __restrict__ Qf, const ushort* __restrict__ Kb,
    const ushort* __restrict__ Vt, float* __restrict__ out) {
  __shared__ __align__(16) char Ksh[64 * 1024];
  __shared__ __align__(16) ushort Psh[32 * 72];     // row stride 144B (pad 8)
  __shared__ float mrow[2][32], pmx[2][32];

  const int bid = blockIdx.x;
  const int b   = bid & 7;                  // batch -> XCD affinity
  const int p   = bid >> 3;                 // 0..63
  const int t   = (p < 32) ? p : (95 - p);  // CU-pair (p, p+32) sums to 63
  const int q0  = t << 5;
  const int tid = threadIdx.x;
  const int w   = tid >> 6;
  const int lane = tid & 63;
  const int g    = (lane >> 4) & 3;
  const int m16  = lane & 15;
  const int qs   = w >> 1;                  // QK^T q-subtile
  const int ks   = w & 1;                   // QK^T k-half (32 of 64)
  const int dw0  = w << 7;                  // PV d-slice base

  const ushort* kbb = Kb + (size_t)b * SDIM * DDIM;
  const ushort* vtb = Vt + (size_t)b * DDIM * SDIM;

  // Q fragments: fp32 -> bf16 in-reg, scaled by 1/sqrt(S)
  const float qscale = 0.022097086912079608f;
  bf16x8 qf[16];
  {
    const float* qrow = Qf + ((size_t)b * SDIM + q0 + qs * 16 + m16) * DDIM + g * 8;
    #pragma unroll
    for (int ds = 0; ds < 16; ++ds) {
      float4 u = *(const float4*)(qrow + ds * 32);
      float4 x = *(const float4*)(qrow + ds * 32 + 4);
      union { ushort us[8]; bf16x8 v; } pk;
      pk.us[0] = f2bf(u.x * qscale); pk.us[1] = f2bf(u.y * qscale);
      pk.us[2] = f2bf(u.z * qscale); pk.us[3] = f2bf(u.w * qscale);
      pk.us[4] = f2bf(x.x * qscale); pk.us[5] = f2bf(x.y * qscale);
      pk.us[6] = f2bf(x.z * qscale); pk.us[7] = f2bf(x.w * qscale);
      qf[ds] = pk.v;
    }
  }

  if (tid < 32) mrow[0][tid] = -1e30f;

  union { ushort us[8]; bf16x8 v; } onesu;
  #pragma unroll
  for (int i = 0; i < 8; ++i) onesu.us[i] = 0x3F80;
  const bf16x8 ones = onesu.v;
  const f32x4 zero = {0.f, 0.f, 0.f, 0.f};
  f32x4 acc[2][8];
  f32x4 acc1[2];
  #pragma unroll
  for (int qt = 0; qt < 2; ++qt) {
    acc1[qt] = zero;
    #pragma unroll
    for (int nt = 0; nt < 8; ++nt) acc[qt][nt] = zero;
  }

  // prologue: stage K tile 0 (64 rows; swizzle byte=(d*2)^((j&7)<<4))
  #pragma unroll
  for (int ji = 0; ji < 16; ++ji) {
    int j = w * 16 + ji;
    const ushort* src = kbb + (size_t)j * DDIM + ((lane ^ (ji & 7)) << 3);
    __builtin_amdgcn_global_load_lds((const AS1 void*)src,
        (AS3 void*)(Ksh + j * 1024), 16, 0, 0);
  }
  asm volatile("s_waitcnt vmcnt(0) lgkmcnt(0)" ::: "memory");
  __builtin_amdgcn_s_barrier();

  const int i_row = q0 + qs * 16 + g * 4;
  const int T = (t + 2) >> 1;               // number of 64-wide k-tiles

  for (int i = 0; i < T; ++i) {
    const int k0 = i << 6;
    const int pp = i & 1;

    // V half 0 (k0..k0+31): full slack until PV half 0
    bf16x8 vb0[8];
    #pragma unroll
    for (int nt = 0; nt < 8; ++nt)
      vb0[nt] = *(const bf16x8*)(vtb + (size_t)(dw0 + nt * 16 + m16) * SDIM + k0 + g * 8);

    // ---- QK^T: 32 rows x 64 k; wave = (qs rows) x (ks 32-k half) ----
    f32x4 sA0 = zero, sA1 = zero, sB0 = zero, sB1 = zero;
    const char* kpA = Ksh + (ks * 32 + m16) * 1024;
    const char* kpB = Ksh + (ks * 32 + 16 + m16) * 1024;
    const unsigned ksw = (unsigned)((m16 & 7) << 4);
    __builtin_amdgcn_s_setprio(1);
    #pragma unroll
    for (int ds = 0; ds < 16; ds += 2) {
      const unsigned o0 = ((unsigned)(ds * 64 + g * 16)) ^ ksw;
      const unsigned o1 = ((unsigned)((ds + 1) * 64 + g * 16)) ^ ksw;
      sA0 = __builtin_amdgcn_mfma_f32_16x16x32_bf16(qf[ds], *(const bf16x8*)(kpA + o0), sA0, 0, 0, 0);
      sB0 = __builtin_amdgcn_mfma_f32_16x16x32_bf16(qf[ds], *(const bf16x8*)(kpB + o0), sB0, 0, 0, 0);
      sA1 = __builtin_amdgcn_mfma_f32_16x16x32_bf16(qf[ds + 1], *(const bf16x8*)(kpA + o1), sA1, 0, 0, 0);
      sB1 = __builtin_amdgcn_mfma_f32_16x16x32_bf16(qf[ds + 1], *(const bf16x8*)(kpB + o1), sB1, 0, 0, 0);
    }
    __builtin_amdgcn_s_setprio(0);

    const bool dia = (i == T - 1);
    float sc[2][4];
    #pragma unroll
    for (int cset = 0; cset < 2; ++cset) {
      const int j_col = k0 + ks * 32 + cset * 16 + m16;
      #pragma unroll
      for (int jj = 0; jj < 4; ++jj) {
        float d = (float)(i_row + jj - j_col);
        float bias = __builtin_amdgcn_rcpf(fmaf(0.2f * d, d, 1.0f));
        float s = (cset ? (sB0[jj] + sB1[jj]) : (sA0[jj] + sA1[jj])) + bias;
        if (dia && (j_col > i_row + jj)) s = -1e30f;
        sc[cset][jj] = s;
      }
    }

    // row max over this wave's 64 k-cols -> pmx[ks]
    #pragma unroll
    for (int jj = 0; jj < 4; ++jj) {
      float v = fmaxf(sc[0][jj], sc[1][jj]);
      v = fmaxf(v, __shfl_xor(v, 1));
      v = fmaxf(v, __shfl_xor(v, 2));
      v = fmaxf(v, __shfl_xor(v, 4));
      v = fmaxf(v, __shfl_xor(v, 8));
      if (m16 == 0) pmx[ks][qs * 16 + g * 4 + jj] = v;
    }
    asm volatile("s_waitcnt lgkmcnt(0)" ::: "memory");
    __builtin_amdgcn_s_barrier();                    // [B] pmax visible; Ksh reads done

    // V half 1 FIRST (so its completion wait is vmcnt(16), K stays in flight)
    bf16x8 vb1[8];
    #pragma unroll
    for (int nt = 0; nt < 8; ++nt)
      vb1[nt] = *(const bf16x8*)(vtb + (size_t)(dw0 + nt * 16 + m16) * SDIM + k0 + 32 + g * 8);

    // restage K(i+1): slack = softmax + PV, waited at [A]
    if (i + 1 < T) {
      #pragma unroll
      for (int ji = 0; ji < 16; ++ji) {
        int j = w * 16 + ji;
        const ushort* src = kbb + (size_t)(k0 + 64 + j) * DDIM + ((lane ^ (ji & 7)) << 3);
        __builtin_amdgcn_global_load_lds((const AS1 void*)src,
            (AS3 void*)(Ksh + j * 1024), 16, 0, 0);
      }
    }

    // ---- online softmax (row = lane&31) ----
    const int row = lane & 31;
    float mo = mrow[pp][row];
    float tm = fmaxf(pmx[0][row], pmx[1][row]);
    bool upd = tm > mo + 8.0f;                       // defer-max THR=8
    float mn = upd ? tm : mo;
    float rr = upd ? __expf(mo - tm) : 1.0f;
    if (w == 0 && lane < 32) mrow[pp ^ 1][row] = mn;

    #pragma unroll
    for (int cset = 0; cset < 2; ++cset)
      #pragma unroll
      for (int jj = 0; jj < 4; ++jj) {
        float mq = __shfl(mn, qs * 16 + g * 4 + jj);
        float pv = __expf(sc[cset][jj] - mq);
        Psh[(qs * 16 + g * 4 + jj) * 72 + ks * 32 + cset * 16 + m16] = f2bf(pv);
      }

    if (!__all(rr == 1.0f)) {
      #pragma unroll
      for (int qt = 0; qt < 2; ++qt)
        #pragma unroll
        for (int jj = 0; jj < 4; ++jj) {
          float r2 = __shfl(rr, qt * 16 + g * 4 + jj);
          #pragma unroll
          for (int nt = 0; nt < 8; ++nt) acc[qt][nt][jj] *= r2;
          acc1[qt][jj] *= r2;
        }
    }
    asm volatile("s_waitcnt lgkmcnt(0)" ::: "memory");
    __builtin_amdgcn_s_barrier();                    // [C] Psh visible

    // ---- PV half 0: O += P[:,0:32] * V[0:32,:] ----
    {
      bf16x8 pa0 = *(const bf16x8*)((const char*)Psh + (0 * 16 + m16) * 144 + g * 16);
      bf16x8 pa1 = *(const bf16x8*)((const char*)Psh + (1 * 16 + m16) * 144 + g * 16);
      __builtin_amdgcn_s_setprio(1);
      #pragma unroll
      for (int nt = 0; nt < 8; ++nt) {
        acc[0][nt] = __builtin_amdgcn_mfma_f32_16x16x32_bf16(pa0, vb0[nt], acc[0][nt], 0, 0, 0);
        acc[1][nt] = __builtin_amdgcn_mfma_f32_16x16x32_bf16(pa1, vb0[nt], acc[1][nt], 0, 0, 0);
      }
      acc1[0] = __builtin_amdgcn_mfma_f32_16x16x32_bf16(pa0, ones, acc1[0], 0, 0, 0);
      acc1[1] = __builtin_amdgcn_mfma_f32_16x16x32_bf16(pa1, ones, acc1[1], 0, 0, 0);
      __builtin_amdgcn_s_setprio(0);
    }
    // ---- PV half 1: O += P[:,32:64] * V[32:64,:] (vb1 wait = vmcnt(16)) ----
    {
      bf16x8 pa0 = *(const bf16x8*)((const char*)Psh + (0 * 16 + m16) * 144 + 64 + g * 16);
      bf16x8 pa1 = *(const bf16x8*)((const char*)Psh + (1 * 16 + m16) * 144 + 64 + g * 16);
      __builtin_amdgcn_s_setprio(1);
      #pragma unroll
      for (int nt = 0; nt < 8; ++nt) {
        acc[0][nt] = __builtin_amdgcn_mfma_f32_16x16x32_bf16(pa0, vb1[nt], acc[0][nt], 0, 0, 0);
        acc[1][nt] = __builtin_amdgcn_mfma_f32_16x16x32_bf16(pa1, vb1[nt], acc[1][nt], 0, 0, 0);
      }
      acc1[0] = __builtin_amdgcn_mfma_f32_16x16x32_bf16(pa0, ones, acc1[0], 0, 0, 0);
      acc1[1] = __builtin_amdgcn_mfma_f32_16x16x32_bf16(pa1, ones, acc1[1], 0, 0, 0);
      __builtin_amdgcn_s_setprio(0);
    }

    // [A] K(i+1) landed; Psh consumed by all waves
    asm volatile("s_waitcnt vmcnt(0) lgkmcnt(0)" ::: "memory");
    __builtin_amdgcn_s_barrier();
  }

  // epilogue: fully register-resident (l = ones-column accumulator)
  #pragma unroll
  for (int qt = 0; qt < 2; ++qt) {
    #pragma unroll
    for (int jj = 0; jj < 4; ++jj) {
      float inv = 1.0f / acc1[qt][jj];
      float* orow = out + ((size_t)b * SDIM + q0 + qt * 16 + g * 4 + jj) * DDIM + dw0 + m16;
      #pragma unroll
      for (int nt = 0; nt < 8; ++nt)
        orow[nt * 16] = acc[qt][nt][jj] * inv;
    }
  }
}

extern "C" void kernel_launch(void* const* d_in, const int* in_sizes, int n_in,
                              void* d_out, int out_size, void* d_ws, size_t ws_size,
                              hipStream_t stream) {
  const float* Q = (const float*)d_in[0];
  const float* K = (const float*)d_in[1];
  const float* V = (const float*)d_in[2];
  float* out = (float*)d_out;
  ushort* Kb = (ushort*)d_ws;                                  // 16.78 MB
  ushort* Vt = Kb + (size_t)NB * SDIM * DDIM;                  // 16.78 MB
  prep<<<3072, 256, 0, stream>>>(K, V, Kb, Vt);
  attn<<<512, 256, 0, stream>>>(Q, Kb, Vt, out);
}